// Round 9
// baseline (44.958 us; speedup 1.0000x reference)
//
#include <hip/hip_runtime.h>

#define KK 4
#define TT 100000
#define NCLS 100
#define NN 4096
#define MARGIN_F 0.2f
#define EPS_F 1e-8f

#define NXCD 8
#define BLOCKS_PER_K 3136            // per k: 3136 blocks * 4 waves * 8 groups = 100352 >= TT
#define NBLOCKS (BLOCKS_PER_K * 2 * 4 / 8 * 8)  // 12544 total (1568 per XCD)
#define NCOPY 64                     // atomic copies, one cache line each
#define ACC_FLOATS (NCOPY * 16)      // 16-float (64B) stride per copy
#define ACC_BYTES (ACC_FLOATS * 4)   // 4 KB
#define HB_BYTES (NN * KK * 128 * 2) // fp16 batch, 4 MB

typedef _Float16 h2 __attribute__((ext_vector_type(2)));
struct H8 { h2 a, b, c, d; };        // 16 B = 8 halves

// fp32->fp16 convert + beta-lookup table + ws accumulator zeroing
__global__ __launch_bounds__(256) void prep(
    const float* __restrict__ src, const int* __restrict__ labels,
    const float* __restrict__ beta,
    _Float16* __restrict__ dst, float* __restrict__ bl, float* __restrict__ ws)
{
    const int i = blockIdx.x * blockDim.x + threadIdx.x;   // 0..262143
    const float4 v0 = ((const float4*)src)[i * 2];
    const float4 v1 = ((const float4*)src)[i * 2 + 1];
    H8 o;
    o.a = h2{(_Float16)v0.x, (_Float16)v0.y};
    o.b = h2{(_Float16)v0.z, (_Float16)v0.w};
    o.c = h2{(_Float16)v1.x, (_Float16)v1.y};
    o.d = h2{(_Float16)v1.z, (_Float16)v1.w};
    ((H8*)dst)[i] = o;

    if (i < KK * NN) {                      // bl[k][n] = beta[k][labels[n]]
        const int n = i >> 2, k = i & 3;
        bl[k * NN + n] = beta[k * NCLS + labels[n]];
    }
    if (i < ACC_FLOATS) ws[i] = 0.f;
}

// xor1 / xor2 within quad via DPP quad_perm (VALU pipe, no DS)
template <int CTRL>
__device__ __forceinline__ float dpp_xor_add(float x) {
    const int xi = __builtin_bit_cast(int, x);
    const int yi = __builtin_amdgcn_update_dpp(0, xi, CTRL, 0xF, 0xF, true);
    return x + __builtin_bit_cast(float, yi);
}
// xor4 via single ds_swizzle level
__device__ __forceinline__ float swz_xor4_add(float x) {
    const int xi = __builtin_bit_cast(int, x);
    const int yi = __builtin_amdgcn_ds_swizzle(xi, 0x101F);
    return x + __builtin_bit_cast(float, yi);
}

// ws layout: ws[c*16 + j], j<4: totals, j in [4,8): counts; c in [0,NCOPY)
__global__ __launch_bounds__(256) void margin_main(
    const _Float16* __restrict__ hb,
    const int* __restrict__ triplets,
    const float* __restrict__ bl,
    float* __restrict__ ws)
{
    __shared__ float s_red[8];
    const int tid  = threadIdx.x;
    const int lane = tid & 63;
    const int wave = tid >> 6;
    const int g    = lane >> 3;       // group in wave (8 lanes/triplet)
    const int s    = lane & 7;        // sub-lane in group

    // XCD-pinned k: blocks round-robin over 8 XCDs; 2 XCDs own each k.
    const int xcd      = blockIdx.x & (NXCD - 1);
    const int k        = xcd >> 1;                                  // 0..3
    const int blk_in_k = ((xcd & 1) * (NBLOCKS / NXCD)) + (blockIdx.x >> 3); // 0..3135

    // exactly ONE triplet per 8-lane group for the whole kernel
    const int t   = blk_in_k * 32 + wave * 8 + g;   // 0..100351
    const bool ok = (t < TT);
    const int tc  = ok ? t : 0;

    const int* tp = triplets + (k * TT + tc) * 3;
    const int i0 = tp[0];
    const int i1 = tp[1];
    const int i2 = tp[2];
    const float b = bl[k * NN + i0];

    const H8* __restrict__ hb8 = (const H8*)hb;
    const H8* a = hb8 + (((i0 << 2) + k) << 4);
    const H8* p = hb8 + (((i1 << 2) + k) << 4);
    const H8* n = hb8 + (((i2 << 2) + k) << 4);

    const H8 a0 = a[s], a1 = a[8 + s];
    const H8 p0 = p[s], p1 = p[8 + s];
    const H8 n0 = n[s], n1 = n[8 + s];

    float sap = 0.f, san = 0.f;
    h2 d;
    d = a0.a - p0.a; sap = __builtin_amdgcn_fdot2(d, d, sap, false);
    d = a0.b - p0.b; sap = __builtin_amdgcn_fdot2(d, d, sap, false);
    d = a0.c - p0.c; sap = __builtin_amdgcn_fdot2(d, d, sap, false);
    d = a0.d - p0.d; sap = __builtin_amdgcn_fdot2(d, d, sap, false);
    d = a1.a - p1.a; sap = __builtin_amdgcn_fdot2(d, d, sap, false);
    d = a1.b - p1.b; sap = __builtin_amdgcn_fdot2(d, d, sap, false);
    d = a1.c - p1.c; sap = __builtin_amdgcn_fdot2(d, d, sap, false);
    d = a1.d - p1.d; sap = __builtin_amdgcn_fdot2(d, d, sap, false);

    d = a0.a - n0.a; san = __builtin_amdgcn_fdot2(d, d, san, false);
    d = a0.b - n0.b; san = __builtin_amdgcn_fdot2(d, d, san, false);
    d = a0.c - n0.c; san = __builtin_amdgcn_fdot2(d, d, san, false);
    d = a0.d - n0.d; san = __builtin_amdgcn_fdot2(d, d, san, false);
    d = a1.a - n1.a; san = __builtin_amdgcn_fdot2(d, d, san, false);
    d = a1.b - n1.b; san = __builtin_amdgcn_fdot2(d, d, san, false);
    d = a1.c - n1.c; san = __builtin_amdgcn_fdot2(d, d, san, false);
    d = a1.d - n1.d; san = __builtin_amdgcn_fdot2(d, d, san, false);

    // 8-lane reduce: xor1, xor2 on VALU (DPP); xor4 one DS level
    sap = dpp_xor_add<0xB1>(sap);   // quad_perm [1,0,3,2]
    san = dpp_xor_add<0xB1>(san);
    sap = dpp_xor_add<0x4E>(sap);   // quad_perm [2,3,0,1]
    san = dpp_xor_add<0x4E>(san);
    sap = swz_xor4_add(sap);
    san = swz_xor4_add(san);

    // tail on all lanes, masked accumulate (no branch)
    const bool act = (s == 0) && ok;
    const float d_ap = sqrtf(sap + EPS_F);
    const float d_an = sqrtf(san + EPS_F);
    const float pl = fmaxf(d_ap - b + MARGIN_F, 0.f);
    const float nl = fmaxf(b - d_an + MARGIN_F, 0.f);
    float lt = act ? (pl + nl) : 0.f;
    float lc = (act && (pl > 0.f || nl > 0.f)) ? 1.f : 0.f;

    // combine the 8 s==0 lanes of this wave
    #pragma unroll
    for (int o = 8; o <= 32; o <<= 1) {
        lt += __shfl_xor(lt, o);
        lc += __shfl_xor(lc, o);
    }
    if (lane == 0) { s_red[wave] = lt; s_red[4 + wave] = lc; }
    __syncthreads();

    if (tid == 0) {
        const float tot = s_red[0] + s_red[1] + s_red[2] + s_red[3];
        const float cnt = s_red[4] + s_red[5] + s_red[6] + s_red[7];
        const int c = (blockIdx.x >> 3) & (NCOPY - 1);
        atomicAdd(&ws[c * 16 + k], tot);
        atomicAdd(&ws[c * 16 + 4 + k], cnt);
    }
}

__global__ void margin_final(const float* __restrict__ ws, float* __restrict__ out) {
    if (threadIdx.x == 0 && blockIdx.x == 0) {
        float acc = 0.f;
        #pragma unroll
        for (int k = 0; k < KK; ++k) {
            float tot = 0.f, cnt = 0.f;
            for (int c = 0; c < NCOPY; ++c) {
                tot += ws[c * 16 + k];
                cnt += ws[c * 16 + 4 + k];
            }
            const float lk = (cnt == 0.f) ? tot : tot / fmaxf(cnt, 1.f);
            acc += lk;
        }
        out[0] = acc / (float)KK;
    }
}

extern "C" void kernel_launch(void* const* d_in, const int* in_sizes, int n_in,
                              void* d_out, int out_size, void* d_ws, size_t ws_size,
                              hipStream_t stream) {
    const float* batch    = (const float*)d_in[0];
    const int*   labels   = (const int*)d_in[1];
    const int*   triplets = (const int*)d_in[2];
    const float* beta     = (const float*)d_in[3];

    float*     ws = (float*)d_ws;
    _Float16*  hb = (_Float16*)((char*)d_ws + ACC_BYTES);
    float*     bl = (float*)((char*)d_ws + ACC_BYTES + HB_BYTES);

    prep<<<1024, 256, 0, stream>>>(batch, labels, beta, hb, bl, ws);
    margin_main<<<NBLOCKS, 256, 0, stream>>>(hb, triplets, bl, ws);
    margin_final<<<1, 64, 0, stream>>>(ws, (float*)d_out);
}